// Round 13
// baseline (383.126 us; speedup 1.0000x reference)
//
#include <hip/hip_runtime.h>
#include <hip/hip_bf16.h>

// Problem: B=8192, D_IN=1024, D_OUT=1024, E=16
#define NB 8192
#define DIN 1024
#define DOUT 1024
#define NE 16

// split-K=2 (8 experts/block), BM=BN=256. K consumed in slabs of 32;
// A/B each have 4 rotating 16KB slab-buffers (depth-3 slab prefetch).
#define BM 256
#define BN 256
#define NT 128  // K-tiles of 64 per block (2 slabs each)

typedef __attribute__((ext_vector_type(8))) short bf16x8;
typedef __attribute__((ext_vector_type(4))) short short4_t;
typedef __attribute__((ext_vector_type(4))) float f32x4;

__device__ __forceinline__ unsigned short f32_to_bf16(float f) {
  unsigned int u = __float_as_uint(f);
  u += 0x7FFFu + ((u >> 16) & 1u);  // RNE
  return (unsigned short)(u >> 16);
}

__device__ __forceinline__ void gl_lds16(const void* gp, void* lp) {
  __builtin_amdgcn_global_load_lds(
      (const __attribute__((address_space(1))) void*)gp,
      (__attribute__((address_space(3))) void*)lp, 16, 0, 0);
}

#define SB __builtin_amdgcn_sched_barrier(0)

// ---------------- Kernel 1: gate softmax (f32) + x -> bf16 cast --------------
__global__ __launch_bounds__(256) void gate_cast_kernel(
    const float* __restrict__ x, const float* __restrict__ Wg,
    const float* __restrict__ bg, float* __restrict__ gout,
    unsigned short* __restrict__ xbf) {
  const int lane = threadIdx.x & 63;
  const int wid = threadIdx.x >> 6;
  const int row = blockIdx.x * 4 + wid;

  const f32x4* xr = (const f32x4*)(x + (size_t)row * DIN);
  f32x4 xv[4];
#pragma unroll
  for (int j = 0; j < 4; ++j) xv[j] = xr[j * 64 + lane];

  float acc[NE];
#pragma unroll
  for (int e = 0; e < NE; ++e) acc[e] = 0.f;

#pragma unroll
  for (int j = 0; j < 4; ++j) {
#pragma unroll
    for (int t = 0; t < 4; ++t) {
      const int i = j * 256 + lane * 4 + t;
      const f32x4* wrow = (const f32x4*)(Wg + (size_t)i * NE);
      const f32x4 w0 = wrow[0], w1 = wrow[1], w2 = wrow[2], w3 = wrow[3];
      const float xx = xv[j][t];
#pragma unroll
      for (int q = 0; q < 4; ++q) {
        acc[q]      = fmaf(xx, w0[q], acc[q]);
        acc[4 + q]  = fmaf(xx, w1[q], acc[4 + q]);
        acc[8 + q]  = fmaf(xx, w2[q], acc[8 + q]);
        acc[12 + q] = fmaf(xx, w3[q], acc[12 + q]);
      }
    }
  }
#pragma unroll
  for (int off = 32; off >= 1; off >>= 1) {
#pragma unroll
    for (int e = 0; e < NE; ++e) acc[e] += __shfl_xor(acc[e], off, 64);
  }
#pragma unroll
  for (int e = 0; e < NE; ++e) acc[e] += bg[e];
  float mx = acc[0];
#pragma unroll
  for (int e = 1; e < NE; ++e) mx = fmaxf(mx, acc[e]);
  float p[NE];
  float s = 0.f;
#pragma unroll
  for (int e = 0; e < NE; ++e) { p[e] = expf(acc[e] - mx); s += p[e]; }
  const float inv = 1.f / s;
  if (lane == 0) {
#pragma unroll
    for (int e = 0; e < NE; ++e) gout[(size_t)row * NE + e] = p[e] * inv;
  }
#pragma unroll
  for (int j = 0; j < 4; ++j) {
    short4_t o;
#pragma unroll
    for (int t = 0; t < 4; ++t) o[t] = (short)f32_to_bf16(xv[j][t]);
    *(short4_t*)(xbf + (size_t)row * DIN + j * 256 + lane * 4) = o;
  }
}

// ------------- Kernel 2: We[e,i,o] f32 -> WeT[e,o,i] bf16 (transpose) --------
__global__ __launch_bounds__(256) void we_transpose_kernel(
    const float* __restrict__ We, unsigned short* __restrict__ WeT) {
  __shared__ float tile[64][65];
  const int e = blockIdx.z, it = blockIdx.y, ot = blockIdx.x;
  const int tr = threadIdx.x >> 4;
  const int tc = (threadIdx.x & 15) * 4;
  const float* src = We + (((size_t)e * DIN + it * 64) * DOUT) + ot * 64;
#pragma unroll
  for (int rr = 0; rr < 64; rr += 16) {
    const f32x4 v = *(const f32x4*)(src + (size_t)(rr + tr) * DOUT + tc);
#pragma unroll
    for (int t = 0; t < 4; ++t) tile[rr + tr][tc + t] = v[t];
  }
  __syncthreads();
  unsigned short* dst = WeT + (((size_t)e * DOUT + ot * 64) * DIN) + it * 64;
#pragma unroll
  for (int rr = 0; rr < 64; rr += 16) {
    short4_t o;
#pragma unroll
    for (int t = 0; t < 4; ++t) o[t] = (short)f32_to_bf16(tile[tc + t][rr + tr]);
    *(short4_t*)(dst + (size_t)(rr + tr) * DIN + tc) = o;
  }
}

// ---- Kernel 3: split-K MoE GEMM, slab-rotated LDS, depth-5/6-phase prefetch -
// 8 waves 2Mx4N, per-wave 128x64. K-slab = 32 cols (16KB/tile-side), 4
// rotating buffers per side. Phases: P0 mi0-3/ks0, P1 mi4-7/ks0 (slab 2t
// retires), P2 mi0-3/ks1, P3 mi4-7/ks1. Stage: P0(t)->slab 2t+3 (needed
// P2(t+1): 6 phases), P3(t)->slab 2t+4 (needed P0(t+2): 5 phases). Waits:
// vmcnt(8) at P0/P2 tops (counted, 2 slabs in flight; tail 4/0). Swizzle:
// slot ^= (row>>1)&3, both sides (stage inverse on global src, read XOR).
// Output: atomicAdd into pre-zeroed out; bias folded per half in epilogue.
__global__ __launch_bounds__(512, 2) void moe_gemm_kernel(
    const unsigned short* __restrict__ xbf,   // [8192][1024] bf16
    const unsigned short* __restrict__ WeT,   // [16][1024 o][1024 i] bf16
    const float* __restrict__ g,              // [8192][16]
    const float* __restrict__ be,             // [16][1024]
    float* __restrict__ out) {                // [8192][1024] f32 (zeroed)
  __shared__ __align__(16) unsigned short As[4][BM * 32];  // 4x16 KiB
  __shared__ __align__(16) unsigned short Bs[4][BN * 32];  // 4x16 KiB
  __shared__ float gs[BM][8];                              // 8 KiB

  const int tid = threadIdx.x;
  const int lane = tid & 63, wid = tid >> 6;
  const int wm = wid >> 2, wn = wid & 3;
  const int l15 = lane & 15, l4 = lane >> 4;

  const int bid = blockIdx.x;
  const int xcd = bid & 7, jj_ = bid >> 3;
  const int kh = xcd >> 2;
  const int brow = ((xcd & 3) * 8 + (jj_ >> 2)) * BM;
  const int bcol = (jj_ & 3) * BN;

  // LDS read bases: row = 64B (4 slots of 16B); physical slot = l4 ^ ((r>>1)&3)
  const int swzr = (l4 ^ ((l15 >> 1) & 3)) << 4;
  const int ldsAoff = (wm * 128 + l15) * 64 + swzr;  // + mi*1024 + buf*16384
  const int ldsBoff = (wn * 64 + l15) * 64 + swzr;   // + ni*1024 + buf*16384
  const char* const AsB = (const char*)&As[0][0];
  const char* const BsB = (const char*)&Bs[0][0];

  // staging: chunk = 8KB = 128 rows x 32 k; thread -> (srow=tid>>2, slot=tid&3)
  const int srow = tid >> 2;
  const int lk = (((tid & 3) ^ ((srow >> 1) & 3)) << 3);  // k-elem in slab
  const unsigned short* const aB = xbf + (size_t)(brow + srow) * DIN + lk;
  const unsigned short* const bB = WeT + (size_t)(bcol + srow) * DIN + lk;
  char* const dstA = (char*)&As[0][0] + wid * 1024;  // wave-uniform
  char* const dstB = (char*)&Bs[0][0] + wid * 1024;

#define STSLAB(BUFI, S)                                                  \
  {                                                                      \
    const int kc_ = ((S) & 31) * 32;                                     \
    const size_t eo_ = (size_t)(kh * 8 + ((S) >> 5)) * (size_t)(DIN * DOUT); \
    gl_lds16(aB + kc_, dstA + (BUFI) * 16384);                           \
    gl_lds16(aB + 131072 + kc_, dstA + (BUFI) * 16384 + 8192);           \
    gl_lds16(bB + eo_ + kc_, dstB + (BUFI) * 16384);                     \
    gl_lds16(bB + eo_ + 131072 + kc_, dstB + (BUFI) * 16384 + 8192);     \
  }
#define RD_B(BI)                                                  \
  _Pragma("unroll") for (int ni = 0; ni < 4; ++ni)                \
      bfr[ni] = *(const bf16x8*)(BsB + (BI) * 16384 + ldsBoff + ni * 1024);
#define RD_A(MI0, BI)                                             \
  _Pragma("unroll") for (int d = 0; d < 4; ++d)                   \
      af[d] = *(const bf16x8*)(AsB + (BI) * 16384 + ldsAoff + ((MI0) + d) * 1024);
#define MFMA_P(MI0)                                                \
  _Pragma("unroll") for (int d = 0; d < 4; ++d)                    \
  _Pragma("unroll") for (int ni = 0; ni < 4; ++ni)                 \
      acc[(MI0) + d][ni] = __builtin_amdgcn_mfma_f32_16x16x32_bf16(\
          af[d], bfr[ni], acc[(MI0) + d][ni], 0, 0, 0);

  {  // gate tile -> LDS: gs[row][e8] = g[brow+row][kh*8+e8]
    const float* gsrc = g + (size_t)brow * NE + kh * 8;
    const int grow = tid >> 1, gh = tid & 1;
    const f32x4 v = *(const f32x4*)(gsrc + (size_t)grow * NE + gh * 4);
    ((f32x4*)&gs[0][0])[tid] = v;
  }

  // prologue: stage slabs 0,1,2 into bufs 0,1,2 (12 loads in flight)
  STSLAB(0, 0);
  STSLAB(1, 1);
  STSLAB(2, 2);

  f32x4 acc[8][4];
#pragma unroll
  for (int mi = 0; mi < 8; ++mi)
#pragma unroll
    for (int ni = 0; ni < 4; ++ni) acc[mi][ni] = (f32x4){0.f, 0.f, 0.f, 0.f};

  bf16x8 bfr[4], af[4];

#define TILE_BODY(T, B0, B1, S0B, S3B)                                         \
  {                                                                            \
    const int t_ = (T);                                                        \
    if ((t_ & 15) == 0 && t_ > 0) { /* expert boundary rescale */              \
      const int e8 = t_ >> 4;                                                  \
      _Pragma("unroll") for (int mi = 0; mi < 8; ++mi) {                       \
        const int rb = wm * 128 + mi * 16 + l4 * 4;                            \
        _Pragma("unroll") for (int q = 0; q < 4; ++q) {                        \
          const float r = gs[rb + q][e8 - 1] *                                 \
                          __builtin_amdgcn_rcpf(fmaxf(gs[rb + q][e8], 1e-30f));\
          _Pragma("unroll") for (int ni = 0; ni < 4; ++ni)                     \
              acc[mi][ni][q] *= r;                                             \
        }                                                                      \
      }                                                                        \
    }                                                                          \
    /* ===== P0: mi0-3, slab 2t ===== */                                       \
    if (t_ < NT - 1) { asm volatile("s_waitcnt vmcnt(8)" ::: "memory"); }      \
    else             { asm volatile("s_waitcnt vmcnt(4)" ::: "memory"); }      \
    SB;                                                                        \
    RD_B(B0); RD_A(0, B0);                                                     \
    if (t_ <= NT - 2) STSLAB(S0B, 2 * t_ + 3);                                 \
    __builtin_amdgcn_s_barrier(); SB;                                          \
    __builtin_amdgcn_s_setprio(1); MFMA_P(0);                                  \
    __builtin_amdgcn_s_setprio(0);                                             \
    /* ===== P1: mi4-7, slab 2t (slab retires) ===== */                        \
    RD_A(4, B0);                                                               \
    __builtin_amdgcn_s_barrier(); SB;                                          \
    __builtin_amdgcn_s_setprio(1); MFMA_P(4);                                  \
    __builtin_amdgcn_s_setprio(0);                                             \
    /* ===== P2: mi0-3, slab 2t+1 ===== */                                     \
    if (t_ < NT - 1) { asm volatile("s_waitcnt vmcnt(8)" ::: "memory"); }      \
    else             { asm volatile("s_waitcnt vmcnt(0)" ::: "memory"); }      \
    SB;                                                                        \
    RD_B(B1); RD_A(0, B1);                                                     \
    __builtin_amdgcn_s_barrier(); SB;                                          \
    __builtin_amdgcn_s_setprio(1); MFMA_P(0);                                  \
    __builtin_amdgcn_s_setprio(0);                                             \
    /* ===== P3: mi4-7, slab 2t+1; stage slab 2t+4 ===== */                    \
    RD_A(4, B1);                                                               \
    if (t_ <= NT - 3) STSLAB(S3B, 2 * t_ + 4);                                 \
    __builtin_amdgcn_s_barrier(); SB;                                          \
    __builtin_amdgcn_s_setprio(1); MFMA_P(4);                                  \
    __builtin_amdgcn_s_setprio(0);                                             \
    if ((t_ & 15) == 15) { /* bias for expert e8 */                            \
      const int e = kh * 8 + (t_ >> 4);                                        \
      _Pragma("unroll") for (int ni = 0; ni < 4; ++ni) {                       \
        const float bv = be[e * DOUT + bcol + wn * 64 + ni * 16 + l15];        \
        _Pragma("unroll") for (int mi = 0; mi < 8; ++mi)                       \
          _Pragma("unroll") for (int q = 0; q < 4; ++q)                        \
              acc[mi][ni][q] += bv;                                            \
      }                                                                        \
    }                                                                          \
  }

  for (int tt = 0; tt < NT; tt += 2) {
    TILE_BODY(tt, 0, 1, 3, 0);
    TILE_BODY(tt + 1, 2, 3, 1, 2);
  }

  // epilogue: atomicAdd acc*g[7] + sum_{e8} g[e8]*be[e,col] into out
  float bv[8][4];
#pragma unroll
  for (int e8 = 0; e8 < 8; ++e8)
#pragma unroll
    for (int ni = 0; ni < 4; ++ni)
      bv[e8][ni] = be[(kh * 8 + e8) * DOUT + bcol + wn * 64 + ni * 16 + l15];
#pragma unroll
  for (int mi = 0; mi < 8; ++mi) {
    const int rb = wm * 128 + mi * 16 + l4 * 4;
#pragma unroll
    for (int q = 0; q < 4; ++q) {
      const int row = rb + q;
      const float gf = gs[row][7];
      float b0 = 0.f, b1 = 0.f, b2 = 0.f, b3 = 0.f;
#pragma unroll
      for (int e8 = 0; e8 < 8; ++e8) {
        const float ge = gs[row][e8];
        b0 = fmaf(ge, bv[e8][0], b0);
        b1 = fmaf(ge, bv[e8][1], b1);
        b2 = fmaf(ge, bv[e8][2], b2);
        b3 = fmaf(ge, bv[e8][3], b3);
      }
      float* const orp =
          out + (size_t)(brow + row) * DOUT + bcol + wn * 64 + l15;
      atomicAdd(orp,      fmaf(acc[mi][0][q], gf, b0));
      atomicAdd(orp + 16, fmaf(acc[mi][1][q], gf, b1));
      atomicAdd(orp + 32, fmaf(acc[mi][2][q], gf, b2));
      atomicAdd(orp + 48, fmaf(acc[mi][3][q], gf, b3));
    }
  }
#undef TILE_BODY
#undef MFMA_P
#undef RD_A
#undef RD_B
#undef STSLAB
}

// ---------------------------------------------------------------------------
extern "C" void kernel_launch(void* const* d_in, const int* in_sizes, int n_in,
                              void* d_out, int out_size, void* d_ws, size_t ws_size,
                              hipStream_t stream) {
  const float* x  = (const float*)d_in[0];
  const float* Wg = (const float*)d_in[1];
  const float* bg = (const float*)d_in[2];
  const float* We = (const float*)d_in[3];
  const float* be = (const float*)d_in[4];
  float* out = (float*)d_out;

  // ws: xbf 16MB | WeT 32MB | g 512KB
  char* ws = (char*)d_ws;
  unsigned short* xbf = (unsigned short*)ws;
  unsigned short* WeT = (unsigned short*)(ws + (size_t)NB * DIN * 2);
  float* g = (float*)(ws + (size_t)NB * DIN * 2 + (size_t)NE * DIN * DOUT * 2);

  hipMemsetAsync(out, 0, (size_t)NB * DOUT * sizeof(float), stream);
  gate_cast_kernel<<<dim3(NB / 4), 256, 0, stream>>>(x, Wg, bg, g, xbf);
  we_transpose_kernel<<<dim3(DOUT / 64, DIN / 64, NE), 256, 0, stream>>>(We, WeT);
  moe_gemm_kernel<<<dim3(256), 512, 0, stream>>>(xbf, WeT, g, be, out);
}

// Round 14
// 370.167 us; speedup vs baseline: 1.0350x; 1.0350x over previous
//
#include <hip/hip_runtime.h>
#include <hip/hip_bf16.h>

// Problem: B=8192, D_IN=1024, D_OUT=1024, E=16
#define NB 8192
#define DIN 1024
#define DOUT 1024
#define NE 16

// GEMM tile geometry: split-K=2 (8 experts per block), BM=BN=256, BK=64
#define BM 256
#define BN 256
#define BK 64
#define NT 128  // (8 experts * 1024) / 64

typedef __attribute__((ext_vector_type(8))) short bf16x8;
typedef __attribute__((ext_vector_type(4))) short short4_t;
typedef __attribute__((ext_vector_type(4))) float f32x4;

__device__ __forceinline__ unsigned short f32_to_bf16(float f) {
  unsigned int u = __float_as_uint(f);
  u += 0x7FFFu + ((u >> 16) & 1u);  // RNE
  return (unsigned short)(u >> 16);
}

__device__ __forceinline__ void gl_lds16(const void* gp, void* lp) {
  __builtin_amdgcn_global_load_lds(
      (const __attribute__((address_space(1))) void*)gp,
      (__attribute__((address_space(3))) void*)lp, 16, 0, 0);
}

#define SB __builtin_amdgcn_sched_barrier(0)

// ---------------- Kernel 1: gate softmax (f32) + x -> bf16 cast --------------
__global__ __launch_bounds__(256) void gate_cast_kernel(
    const float* __restrict__ x, const float* __restrict__ Wg,
    const float* __restrict__ bg, float* __restrict__ gout,
    unsigned short* __restrict__ xbf) {
  const int lane = threadIdx.x & 63;
  const int wid = threadIdx.x >> 6;
  const int row = blockIdx.x * 4 + wid;

  const f32x4* xr = (const f32x4*)(x + (size_t)row * DIN);
  f32x4 xv[4];
#pragma unroll
  for (int j = 0; j < 4; ++j) xv[j] = xr[j * 64 + lane];

  float acc[NE];
#pragma unroll
  for (int e = 0; e < NE; ++e) acc[e] = 0.f;

#pragma unroll
  for (int j = 0; j < 4; ++j) {
#pragma unroll
    for (int t = 0; t < 4; ++t) {
      const int i = j * 256 + lane * 4 + t;
      const f32x4* wrow = (const f32x4*)(Wg + (size_t)i * NE);
      const f32x4 w0 = wrow[0], w1 = wrow[1], w2 = wrow[2], w3 = wrow[3];
      const float xx = xv[j][t];
#pragma unroll
      for (int q = 0; q < 4; ++q) {
        acc[q]      = fmaf(xx, w0[q], acc[q]);
        acc[4 + q]  = fmaf(xx, w1[q], acc[4 + q]);
        acc[8 + q]  = fmaf(xx, w2[q], acc[8 + q]);
        acc[12 + q] = fmaf(xx, w3[q], acc[12 + q]);
      }
    }
  }
#pragma unroll
  for (int off = 32; off >= 1; off >>= 1) {
#pragma unroll
    for (int e = 0; e < NE; ++e) acc[e] += __shfl_xor(acc[e], off, 64);
  }
#pragma unroll
  for (int e = 0; e < NE; ++e) acc[e] += bg[e];
  float mx = acc[0];
#pragma unroll
  for (int e = 1; e < NE; ++e) mx = fmaxf(mx, acc[e]);
  float p[NE];
  float s = 0.f;
#pragma unroll
  for (int e = 0; e < NE; ++e) { p[e] = expf(acc[e] - mx); s += p[e]; }
  const float inv = 1.f / s;
  if (lane == 0) {
#pragma unroll
    for (int e = 0; e < NE; ++e) gout[(size_t)row * NE + e] = p[e] * inv;
  }
#pragma unroll
  for (int j = 0; j < 4; ++j) {
    short4_t o;
#pragma unroll
    for (int t = 0; t < 4; ++t) o[t] = (short)f32_to_bf16(xv[j][t]);
    *(short4_t*)(xbf + (size_t)row * DIN + j * 256 + lane * 4) = o;
  }
}

// ------------- Kernel 2: We[e,i,o] f32 -> WeT[e,o,i] bf16 (transpose) --------
__global__ __launch_bounds__(256) void we_transpose_kernel(
    const float* __restrict__ We, unsigned short* __restrict__ WeT) {
  __shared__ float tile[64][65];
  const int e = blockIdx.z, it = blockIdx.y, ot = blockIdx.x;
  const int tr = threadIdx.x >> 4;
  const int tc = (threadIdx.x & 15) * 4;
  const float* src = We + (((size_t)e * DIN + it * 64) * DOUT) + ot * 64;
#pragma unroll
  for (int rr = 0; rr < 64; rr += 16) {
    const f32x4 v = *(const f32x4*)(src + (size_t)(rr + tr) * DOUT + tc);
#pragma unroll
    for (int t = 0; t < 4; ++t) tile[rr + tr][tc + t] = v[t];
  }
  __syncthreads();
  unsigned short* dst = WeT + (((size_t)e * DOUT + ot * 64) * DIN) + it * 64;
#pragma unroll
  for (int rr = 0; rr < 64; rr += 16) {
    short4_t o;
#pragma unroll
    for (int t = 0; t < 4; ++t) o[t] = (short)f32_to_bf16(tile[tc + t][rr + tr]);
    *(short4_t*)(dst + (size_t)(rr + tr) * DIN + tc) = o;
  }
}

// ------------- Kernel 3: split-K MoE GEMM, 4 phases (r8 best body) -----------
// 8 waves 2Mx4N, per-wave 128x64. P0 mi0-3/ks0, P1 mi0-3/ks1, P2 mi4-7/ks0,
// P3 mi4-7/ks1. One pre-MFMA barrier per phase + one boundary barrier.
// Minimal sched pins (one SB after each s_barrier). Stage for t+1: P0 Bh0,
// P1 Bh1, P2 Ah0, P3 Ah1. Waits: end-P1 vmcnt(4), boundary vmcnt(2).
// Output: atomicAdd into pre-zeroed out (both kh halves).
__global__ __launch_bounds__(512, 2) void moe_gemm_kernel(
    const unsigned short* __restrict__ xbf,   // [8192][1024] bf16
    const unsigned short* __restrict__ WeT,   // [16][1024 o][1024 i] bf16
    const float* __restrict__ g,              // [8192][16]
    const float* __restrict__ be,             // [16][1024]
    float* __restrict__ out) {                // [8192][1024] f32 (zeroed)
  __shared__ __align__(16) unsigned short As[2][BM * BK];  // 2x32 KiB
  __shared__ __align__(16) unsigned short Bs[2][BN * BK];  // 2x32 KiB
  __shared__ float gs[BM][NE];                             // 16 KiB

  const int tid = threadIdx.x;
  const int lane = tid & 63, wid = tid >> 6;
  const int wm = wid >> 2, wn = wid & 3;
  const int l15 = lane & 15, l4 = lane >> 4;

  const int bid = blockIdx.x;
  const int xcd = bid & 7, jj_ = bid >> 3;
  const int kh = xcd >> 2;
  const int brow = ((xcd & 3) * 8 + (jj_ >> 2)) * BM;
  const int bcol = (jj_ & 3) * BN;

  // precomputed per-thread LDS read bases; swizzle depends only on (l15,l4,ks)
  const int swz0 = (l4 * 16) ^ ((l15 & 7) << 4);
  const int swz1 = (64 + l4 * 16) ^ ((l15 & 7) << 4);
  const char* const ldsA0 = (const char*)&As[0][0] + (wm * 128 + l15) * 128 + swz0;
  const char* const ldsA1 = (const char*)&As[0][0] + (wm * 128 + l15) * 128 + swz1;
  const char* const ldsB0 = (const char*)&Bs[0][0] + (wn * 64 + l15) * 128 + swz0;
  const char* const ldsB1 = (const char*)&Bs[0][0] + (wn * 64 + l15) * 128 + swz1;

  // staging precompute (T2 both-sides: linear LDS dst, inverse-swz global src)
  const int srow = tid >> 3;
  const int lk = (((tid & 7) * 16) ^ ((srow & 7) << 4)) >> 1;
  const unsigned short* const aBase = xbf + (size_t)(brow + srow) * DIN + lk;
  const unsigned short* const bBase = WeT + (size_t)(bcol + srow) * DIN + lk;
  char* const ldsStA = (char*)&As[0][0] + wid * 1024;  // wave-uniform
  char* const ldsStB = (char*)&Bs[0][0] + wid * 1024;

#define STA(BUF, CR, KC) \
  gl_lds16(aBase + (size_t)(CR) * DIN + (KC), ldsStA + (BUF) * 32768 + (CR) * 128)
#define STB(BUF, CR, EOFF, KC) \
  gl_lds16(bBase + (EOFF) + (size_t)(CR) * DIN + (KC), \
           ldsStB + (BUF) * 32768 + (CR) * 128)
#define RD_B(KS, BUF)                                             \
  _Pragma("unroll") for (int ni = 0; ni < 4; ++ni)                \
      bfr[ni][KS] = *(const bf16x8*)(((KS) ? ldsB1 : ldsB0) +     \
                                     ni * 2048 + (BUF) * 32768);
#define RD_A(KS, MI0, BUF)                                        \
  _Pragma("unroll") for (int d = 0; d < 4; ++d)                   \
      af[d] = *(const bf16x8*)(((KS) ? ldsA1 : ldsA0) +           \
                               ((MI0) + d) * 2048 + (BUF) * 32768);
#define MFMA_P(MI0, KS)                                            \
  _Pragma("unroll") for (int d = 0; d < 4; ++d)                    \
  _Pragma("unroll") for (int ni = 0; ni < 4; ++ni)                 \
      acc[(MI0) + d][ni] = __builtin_amdgcn_mfma_f32_16x16x32_bf16(\
          af[d], bfr[ni][KS], acc[(MI0) + d][ni], 0, 0, 0);

  {  // gate tile -> LDS
    const f32x4* gsrc = (const f32x4*)(g + (size_t)brow * NE);
    f32x4* gdst = (f32x4*)&gs[0][0];
    gdst[tid] = gsrc[tid];
    gdst[tid + 512] = gsrc[tid + 512];
  }

  // prologue: stage tile 0, deadline order Bh0,Bh1,Ah0 then Ah1
  {
    const size_t e0 = (size_t)(kh * 8) * (size_t)(DIN * DOUT);
    STB(0, 0, e0, 0);  STB(0, 128, e0, 0);
    STB(0, 64, e0, 0); STB(0, 192, e0, 0);
    STA(0, 0, 0);      STA(0, 128, 0);
    STA(0, 64, 0);     STA(0, 192, 0);
  }

  f32x4 acc[8][4];
#pragma unroll
  for (int mi = 0; mi < 8; ++mi)
#pragma unroll
    for (int ni = 0; ni < 4; ++ni) acc[mi][ni] = (f32x4){0.f, 0.f, 0.f, 0.f};

  asm volatile("s_waitcnt vmcnt(2) lgkmcnt(0)" ::: "memory");
  __builtin_amdgcn_s_barrier(); SB;

  bf16x8 bfr[4][2], af[4];

#define TILE_BODY(T, BUF)                                                      \
  {                                                                            \
    const int t_ = (T);                                                        \
    const int kcN = ((t_ + 1) & 15) * 64;                                      \
    const size_t eoffN =                                                       \
        (size_t)(kh * 8 + ((t_ + 1) >> 4)) * (size_t)(DIN * DOUT);             \
    const bool hasNext = (t_ + 1) < NT;                                        \
    if ((t_ & 15) == 0 && t_ > 0) { /* expert boundary rescale */              \
      const int e = kh * 8 + (t_ >> 4);                                        \
      _Pragma("unroll") for (int mi = 0; mi < 8; ++mi) {                       \
        const int rb = wm * 128 + mi * 16 + l4 * 4;                            \
        _Pragma("unroll") for (int q = 0; q < 4; ++q) {                        \
          const float r = gs[rb + q][e - 1] *                                  \
                          __builtin_amdgcn_rcpf(fmaxf(gs[rb + q][e], 1e-30f)); \
          _Pragma("unroll") for (int ni = 0; ni < 4; ++ni)                     \
              acc[mi][ni][q] *= r;                                             \
        }                                                                      \
      }                                                                        \
    }                                                                          \
    /* ===== P0: mi0-3, ks0 ===== */                                           \
    RD_B(0, BUF); RD_A(0, 0, BUF);                                             \
    if (hasNext) { STB(BUF ^ 1, 0, eoffN, kcN); STB(BUF ^ 1, 128, eoffN, kcN); } \
    __builtin_amdgcn_s_barrier(); SB;                                          \
    __builtin_amdgcn_s_setprio(1); MFMA_P(0, 0);                               \
    __builtin_amdgcn_s_setprio(0);                                             \
    /* ===== P1: mi0-3, ks1 ===== */                                           \
    RD_B(1, BUF); RD_A(1, 0, BUF);                                             \
    if (hasNext) { STB(BUF ^ 1, 64, eoffN, kcN); STB(BUF ^ 1, 192, eoffN, kcN); } \
    if (t_ == NT - 1) { asm volatile("s_waitcnt vmcnt(0)" ::: "memory"); }     \
    else { asm volatile("s_waitcnt vmcnt(4)" ::: "memory"); }                  \
    __builtin_amdgcn_s_barrier(); SB;                                          \
    __builtin_amdgcn_s_setprio(1); MFMA_P(0, 1);                               \
    __builtin_amdgcn_s_setprio(0);                                             \
    /* ===== P2: mi4-7, ks0 ===== */                                           \
    RD_A(0, 4, BUF);                                                           \
    if (hasNext) { STA(BUF ^ 1, 0, kcN); STA(BUF ^ 1, 128, kcN); }             \
    __builtin_amdgcn_s_barrier(); SB;                                          \
    __builtin_amdgcn_s_setprio(1); MFMA_P(4, 0);                               \
    __builtin_amdgcn_s_setprio(0);                                             \
    /* ===== P3: mi4-7, ks1 ===== */                                           \
    RD_A(1, 4, BUF);                                                           \
    if (hasNext) { STA(BUF ^ 1, 64, kcN); STA(BUF ^ 1, 192, kcN); }            \
    __builtin_amdgcn_s_barrier(); SB;                                          \
    __builtin_amdgcn_s_setprio(1); MFMA_P(4, 1);                               \
    __builtin_amdgcn_s_setprio(0);                                             \
    if ((t_ & 15) == 15) { /* bias for expert e: coeff ends as g[r,e] */       \
      const int e = kh * 8 + (t_ >> 4);                                        \
      _Pragma("unroll") for (int ni = 0; ni < 4; ++ni) {                       \
        const float bv = be[e * DOUT + bcol + wn * 64 + ni * 16 + l15];        \
        _Pragma("unroll") for (int mi = 0; mi < 8; ++mi)                       \
          _Pragma("unroll") for (int q = 0; q < 4; ++q)                        \
              acc[mi][ni][q] += bv;                                            \
      }                                                                        \
    }                                                                          \
    if (t_ < NT - 1) { asm volatile("s_waitcnt vmcnt(2)" ::: "memory"); }      \
    __builtin_amdgcn_s_barrier(); SB;                                          \
  }

  for (int tt = 0; tt < NT; tt += 2) {
    TILE_BODY(tt, 0);
    TILE_BODY(tt + 1, 1);
  }

  // epilogue: atomicAdd acc * g[r, last expert of this half] into zeroed out
  const int eL = kh * 8 + 7;
#pragma unroll
  for (int mi = 0; mi < 8; ++mi) {
    const int rb = wm * 128 + mi * 16 + l4 * 4;
#pragma unroll
    for (int q = 0; q < 4; ++q) {
      const float gf = gs[rb + q][eL];
      float* const orp =
          out + (size_t)(brow + rb + q) * DOUT + bcol + wn * 64 + l15;
      atomicAdd(orp,      acc[mi][0][q] * gf);
      atomicAdd(orp + 16, acc[mi][1][q] * gf);
      atomicAdd(orp + 32, acc[mi][2][q] * gf);
      atomicAdd(orp + 48, acc[mi][3][q] * gf);
    }
  }
#undef TILE_BODY
#undef MFMA_P
#undef RD_A
#undef RD_B
#undef STA
#undef STB
}

// ---------------------------------------------------------------------------
extern "C" void kernel_launch(void* const* d_in, const int* in_sizes, int n_in,
                              void* d_out, int out_size, void* d_ws, size_t ws_size,
                              hipStream_t stream) {
  const float* x  = (const float*)d_in[0];
  const float* Wg = (const float*)d_in[1];
  const float* bg = (const float*)d_in[2];
  const float* We = (const float*)d_in[3];
  const float* be = (const float*)d_in[4];
  float* out = (float*)d_out;

  // ws: xbf 16MB | WeT 32MB | g 512KB
  char* ws = (char*)d_ws;
  unsigned short* xbf = (unsigned short*)ws;
  unsigned short* WeT = (unsigned short*)(ws + (size_t)NB * DIN * 2);
  float* g = (float*)(ws + (size_t)NB * DIN * 2 + (size_t)NE * DIN * DOUT * 2);

  hipMemsetAsync(out, 0, (size_t)NB * DOUT * sizeof(float), stream);
  gate_cast_kernel<<<dim3(NB / 4), 256, 0, stream>>>(x, Wg, bg, g, xbf);
  we_transpose_kernel<<<dim3(DOUT / 64, DIN / 64, NE), 256, 0, stream>>>(We, WeT);
  moe_gemm_kernel<<<dim3(256), 512, 0, stream>>>(xbf, WeT, g, be, out);
}

// Round 15
// 339.514 us; speedup vs baseline: 1.1285x; 1.0903x over previous
//
#include <hip/hip_runtime.h>
#include <hip/hip_bf16.h>

// Problem: B=8192, D_IN=1024, D_OUT=1024, E=16
#define NB 8192
#define DIN 1024
#define DOUT 1024
#define NE 16

// GEMM tile geometry: split-K=2 (8 experts per block), BM=BN=256, BK=64
#define BM 256
#define BN 256
#define BK 64
#define NT 128  // (8 experts * 1024) / 64

typedef __attribute__((ext_vector_type(8))) short bf16x8;
typedef __attribute__((ext_vector_type(4))) short short4_t;
typedef __attribute__((ext_vector_type(4))) float f32x4;

__device__ __forceinline__ unsigned short f32_to_bf16(float f) {
  unsigned int u = __float_as_uint(f);
  u += 0x7FFFu + ((u >> 16) & 1u);  // RNE
  return (unsigned short)(u >> 16);
}

__device__ __forceinline__ void gl_lds16(const void* gp, void* lp) {
  __builtin_amdgcn_global_load_lds(
      (const __attribute__((address_space(1))) void*)gp,
      (__attribute__((address_space(3))) void*)lp, 16, 0, 0);
}

#define SB __builtin_amdgcn_sched_barrier(0)

// ---------------- Kernel 1: gate softmax (f32) + x -> bf16 cast --------------
__global__ __launch_bounds__(256) void gate_cast_kernel(
    const float* __restrict__ x, const float* __restrict__ Wg,
    const float* __restrict__ bg, float* __restrict__ gout,
    unsigned short* __restrict__ xbf) {
  const int lane = threadIdx.x & 63;
  const int wid = threadIdx.x >> 6;
  const int row = blockIdx.x * 4 + wid;

  const f32x4* xr = (const f32x4*)(x + (size_t)row * DIN);
  f32x4 xv[4];
#pragma unroll
  for (int j = 0; j < 4; ++j) xv[j] = xr[j * 64 + lane];

  float acc[NE];
#pragma unroll
  for (int e = 0; e < NE; ++e) acc[e] = 0.f;

#pragma unroll
  for (int j = 0; j < 4; ++j) {
#pragma unroll
    for (int t = 0; t < 4; ++t) {
      const int i = j * 256 + lane * 4 + t;
      const f32x4* wrow = (const f32x4*)(Wg + (size_t)i * NE);
      const f32x4 w0 = wrow[0], w1 = wrow[1], w2 = wrow[2], w3 = wrow[3];
      const float xx = xv[j][t];
#pragma unroll
      for (int q = 0; q < 4; ++q) {
        acc[q]      = fmaf(xx, w0[q], acc[q]);
        acc[4 + q]  = fmaf(xx, w1[q], acc[4 + q]);
        acc[8 + q]  = fmaf(xx, w2[q], acc[8 + q]);
        acc[12 + q] = fmaf(xx, w3[q], acc[12 + q]);
      }
    }
  }
#pragma unroll
  for (int off = 32; off >= 1; off >>= 1) {
#pragma unroll
    for (int e = 0; e < NE; ++e) acc[e] += __shfl_xor(acc[e], off, 64);
  }
#pragma unroll
  for (int e = 0; e < NE; ++e) acc[e] += bg[e];
  float mx = acc[0];
#pragma unroll
  for (int e = 1; e < NE; ++e) mx = fmaxf(mx, acc[e]);
  float p[NE];
  float s = 0.f;
#pragma unroll
  for (int e = 0; e < NE; ++e) { p[e] = expf(acc[e] - mx); s += p[e]; }
  const float inv = 1.f / s;
  if (lane == 0) {
#pragma unroll
    for (int e = 0; e < NE; ++e) gout[(size_t)row * NE + e] = p[e] * inv;
  }
#pragma unroll
  for (int j = 0; j < 4; ++j) {
    short4_t o;
#pragma unroll
    for (int t = 0; t < 4; ++t) o[t] = (short)f32_to_bf16(xv[j][t]);
    *(short4_t*)(xbf + (size_t)row * DIN + j * 256 + lane * 4) = o;
  }
}

// ------------- Kernel 2: We[e,i,o] f32 -> WeT[e,o,i] bf16 (transpose) --------
__global__ __launch_bounds__(256) void we_transpose_kernel(
    const float* __restrict__ We, unsigned short* __restrict__ WeT) {
  __shared__ float tile[64][65];
  const int e = blockIdx.z, it = blockIdx.y, ot = blockIdx.x;
  const int tr = threadIdx.x >> 4;
  const int tc = (threadIdx.x & 15) * 4;
  const float* src = We + (((size_t)e * DIN + it * 64) * DOUT) + ot * 64;
#pragma unroll
  for (int rr = 0; rr < 64; rr += 16) {
    const f32x4 v = *(const f32x4*)(src + (size_t)(rr + tr) * DOUT + tc);
#pragma unroll
    for (int t = 0; t < 4; ++t) tile[rr + tr][tc + t] = v[t];
  }
  __syncthreads();
  unsigned short* dst = WeT + (((size_t)e * DOUT + ot * 64) * DIN) + it * 64;
#pragma unroll
  for (int rr = 0; rr < 64; rr += 16) {
    short4_t o;
#pragma unroll
    for (int t = 0; t < 4; ++t) o[t] = (short)f32_to_bf16(tile[tc + t][rr + tr]);
    *(short4_t*)(dst + (size_t)(rr + tr) * DIN + tc) = o;
  }
}

// ------------- Kernel 3: split-K MoE GEMM, 4 phases, 5 barriers/tile ---------
// 8 waves 2Mx4N, per-wave 128x64. P0 mi0-3/ks0, P1 mi0-3/ks1, P2 mi4-7/ks0,
// P3 mi4-7/ks1. One pre-MFMA barrier per phase + one boundary barrier.
// Minimal sched pins: one sched_barrier(0) after each s_barrier. Stage for
// t+1: P0 Bh0, P1 Bh1, P2 Ah0, P3 Ah1. Waits: end-P1 vmcnt(4) (drains this
// tile's Ah1 before P2 reads), boundary vmcnt(2). Never 0 mid-loop.
__global__ __launch_bounds__(512, 2) void moe_gemm_kernel(
    const unsigned short* __restrict__ xbf,   // [8192][1024] bf16
    const unsigned short* __restrict__ WeT,   // [16][1024 o][1024 i] bf16
    const float* __restrict__ g,              // [8192][16]
    const float* __restrict__ be,             // [16][1024]
    float* __restrict__ out0,                 // kh=0 -> d_out
    float* __restrict__ out1) {               // kh=1 -> partial ws
  __shared__ __align__(16) unsigned short As[2][BM * BK];  // 2x32 KiB
  __shared__ __align__(16) unsigned short Bs[2][BN * BK];  // 2x32 KiB
  __shared__ float gs[BM][NE];                             // 16 KiB

  const int tid = threadIdx.x;
  const int lane = tid & 63, wid = tid >> 6;
  const int wm = wid >> 2, wn = wid & 3;
  const int l15 = lane & 15, l4 = lane >> 4;

  const int bid = blockIdx.x;
  const int xcd = bid & 7, jj_ = bid >> 3;
  const int kh = xcd >> 2;
  const int brow = ((xcd & 3) * 8 + (jj_ >> 2)) * BM;
  const int bcol = (jj_ & 3) * BN;
  float* const outp = kh ? out1 : out0;

  // precomputed per-thread LDS read bases; swizzle depends only on (l15,l4,ks)
  const int swz0 = (l4 * 16) ^ ((l15 & 7) << 4);
  const int swz1 = (64 + l4 * 16) ^ ((l15 & 7) << 4);
  const char* const ldsA0 = (const char*)&As[0][0] + (wm * 128 + l15) * 128 + swz0;
  const char* const ldsA1 = (const char*)&As[0][0] + (wm * 128 + l15) * 128 + swz1;
  const char* const ldsB0 = (const char*)&Bs[0][0] + (wn * 64 + l15) * 128 + swz0;
  const char* const ldsB1 = (const char*)&Bs[0][0] + (wn * 64 + l15) * 128 + swz1;

  // staging precompute (T2 both-sides: linear LDS dst, inverse-swz global src)
  const int srow = tid >> 3;
  const int lk = (((tid & 7) * 16) ^ ((srow & 7) << 4)) >> 1;
  const unsigned short* const aBase = xbf + (size_t)(brow + srow) * DIN + lk;
  const unsigned short* const bBase = WeT + (size_t)(bcol + srow) * DIN + lk;
  char* const ldsStA = (char*)&As[0][0] + wid * 1024;  // wave-uniform
  char* const ldsStB = (char*)&Bs[0][0] + wid * 1024;

#define STA(BUF, CR, KC) \
  gl_lds16(aBase + (size_t)(CR) * DIN + (KC), ldsStA + (BUF) * 32768 + (CR) * 128)
#define STB(BUF, CR, EOFF, KC) \
  gl_lds16(bBase + (EOFF) + (size_t)(CR) * DIN + (KC), \
           ldsStB + (BUF) * 32768 + (CR) * 128)
#define RD_B(KS, BUF)                                             \
  _Pragma("unroll") for (int ni = 0; ni < 4; ++ni)                \
      bfr[ni][KS] = *(const bf16x8*)(((KS) ? ldsB1 : ldsB0) +     \
                                     ni * 2048 + (BUF) * 32768);
#define RD_A(KS, MI0, BUF)                                        \
  _Pragma("unroll") for (int d = 0; d < 4; ++d)                   \
      af[d] = *(const bf16x8*)(((KS) ? ldsA1 : ldsA0) +           \
                               ((MI0) + d) * 2048 + (BUF) * 32768);
#define MFMA_P(MI0, KS)                                            \
  _Pragma("unroll") for (int d = 0; d < 4; ++d)                    \
  _Pragma("unroll") for (int ni = 0; ni < 4; ++ni)                 \
      acc[(MI0) + d][ni] = __builtin_amdgcn_mfma_f32_16x16x32_bf16(\
          af[d], bfr[ni][KS], acc[(MI0) + d][ni], 0, 0, 0);

  {  // gate tile -> LDS
    const f32x4* gsrc = (const f32x4*)(g + (size_t)brow * NE);
    f32x4* gdst = (f32x4*)&gs[0][0];
    gdst[tid] = gsrc[tid];
    gdst[tid + 512] = gsrc[tid + 512];
  }

  // prologue: stage tile 0, deadline order Bh0,Bh1,Ah0 then Ah1
  {
    const size_t e0 = (size_t)(kh * 8) * (size_t)(DIN * DOUT);
    STB(0, 0, e0, 0);  STB(0, 128, e0, 0);
    STB(0, 64, e0, 0); STB(0, 192, e0, 0);
    STA(0, 0, 0);      STA(0, 128, 0);
    STA(0, 64, 0);     STA(0, 192, 0);
  }

  f32x4 acc[8][4];
#pragma unroll
  for (int mi = 0; mi < 8; ++mi)
#pragma unroll
    for (int ni = 0; ni < 4; ++ni) acc[mi][ni] = (f32x4){0.f, 0.f, 0.f, 0.f};

  asm volatile("s_waitcnt vmcnt(2) lgkmcnt(0)" ::: "memory");
  __builtin_amdgcn_s_barrier(); SB;

  bf16x8 bfr[4][2], af[4];

#define TILE_BODY(T, BUF)                                                      \
  {                                                                            \
    const int t_ = (T);                                                        \
    const int kcN = ((t_ + 1) & 15) * 64;                                      \
    const size_t eoffN =                                                       \
        (size_t)(kh * 8 + ((t_ + 1) >> 4)) * (size_t)(DIN * DOUT);             \
    const bool hasNext = (t_ + 1) < NT;                                        \
    if ((t_ & 15) == 0 && t_ > 0) { /* expert boundary rescale */              \
      const int e = kh * 8 + (t_ >> 4);                                        \
      _Pragma("unroll") for (int mi = 0; mi < 8; ++mi) {                       \
        const int rb = wm * 128 + mi * 16 + l4 * 4;                            \
        _Pragma("unroll") for (int q = 0; q < 4; ++q) {                        \
          const float r = gs[rb + q][e - 1] *                                  \
                          __builtin_amdgcn_rcpf(fmaxf(gs[rb + q][e], 1e-30f)); \
          _Pragma("unroll") for (int ni = 0; ni < 4; ++ni)                     \
              acc[mi][ni][q] *= r;                                             \
        }                                                                      \
      }                                                                        \
    }                                                                          \
    /* ===== P0: mi0-3, ks0 ===== */                                           \
    RD_B(0, BUF); RD_A(0, 0, BUF);                                             \
    if (hasNext) { STB(BUF ^ 1, 0, eoffN, kcN); STB(BUF ^ 1, 128, eoffN, kcN); } \
    __builtin_amdgcn_s_barrier(); SB;                                          \
    __builtin_amdgcn_s_setprio(1); MFMA_P(0, 0);                               \
    __builtin_amdgcn_s_setprio(0);                                             \
    /* ===== P1: mi0-3, ks1 ===== */                                           \
    RD_B(1, BUF); RD_A(1, 0, BUF);                                             \
    if (hasNext) { STB(BUF ^ 1, 64, eoffN, kcN); STB(BUF ^ 1, 192, eoffN, kcN); } \
    if (t_ == NT - 1) { asm volatile("s_waitcnt vmcnt(0)" ::: "memory"); }     \
    else { asm volatile("s_waitcnt vmcnt(4)" ::: "memory"); }                  \
    __builtin_amdgcn_s_barrier(); SB;                                          \
    __builtin_amdgcn_s_setprio(1); MFMA_P(0, 1);                               \
    __builtin_amdgcn_s_setprio(0);                                             \
    /* ===== P2: mi4-7, ks0 ===== */                                           \
    RD_A(0, 4, BUF);                                                           \
    if (hasNext) { STA(BUF ^ 1, 0, kcN); STA(BUF ^ 1, 128, kcN); }             \
    __builtin_amdgcn_s_barrier(); SB;                                          \
    __builtin_amdgcn_s_setprio(1); MFMA_P(4, 0);                               \
    __builtin_amdgcn_s_setprio(0);                                             \
    /* ===== P3: mi4-7, ks1 ===== */                                           \
    RD_A(1, 4, BUF);                                                           \
    if (hasNext) { STA(BUF ^ 1, 64, kcN); STA(BUF ^ 1, 192, kcN); }            \
    __builtin_amdgcn_s_barrier(); SB;                                          \
    __builtin_amdgcn_s_setprio(1); MFMA_P(4, 1);                               \
    __builtin_amdgcn_s_setprio(0);                                             \
    if ((t_ & 15) == 15) { /* bias for expert e */                             \
      const int e = kh * 8 + (t_ >> 4);                                        \
      _Pragma("unroll") for (int ni = 0; ni < 4; ++ni) {                       \
        const float bv = be[e * DOUT + bcol + wn * 64 + ni * 16 + l15];        \
        _Pragma("unroll") for (int mi = 0; mi < 8; ++mi)                       \
          _Pragma("unroll") for (int q = 0; q < 4; ++q)                        \
              acc[mi][ni][q] += bv;                                            \
      }                                                                        \
    }                                                                          \
    if (t_ < NT - 1) { asm volatile("s_waitcnt vmcnt(2)" ::: "memory"); }      \
    __builtin_amdgcn_s_barrier(); SB;                                          \
  }

  for (int tt = 0; tt < NT; tt += 2) {
    TILE_BODY(tt, 0);
    TILE_BODY(tt + 1, 1);
  }

  // epilogue: scale by this half's last gate, store
  const int eL = kh * 8 + 7;
#pragma unroll
  for (int mi = 0; mi < 8; ++mi) {
    const int rb = wm * 128 + mi * 16 + l4 * 4;
#pragma unroll
    for (int q = 0; q < 4; ++q) {
      const float gf = gs[rb + q][eL];
      const size_t orow = (size_t)brow + rb + q;
#pragma unroll
      for (int ni = 0; ni < 4; ++ni)
        outp[orow * DOUT + bcol + wn * 64 + ni * 16 + l15] =
            acc[mi][ni][q] * gf;
    }
  }
#undef TILE_BODY
#undef MFMA_P
#undef RD_A
#undef RD_B
#undef STA
#undef STB
}

// ---------------- Kernel 4: combine out += p1 --------------------------------
__global__ __launch_bounds__(256) void combine_kernel(
    float* __restrict__ out, const float* __restrict__ p1) {
  const size_t i = (size_t)blockIdx.x * 256 + threadIdx.x;  // f32x4 index
  f32x4 a = ((const f32x4*)out)[i];
  const f32x4 b = ((const f32x4*)p1)[i];
#pragma unroll
  for (int q = 0; q < 4; ++q) a[q] += b[q];
  ((f32x4*)out)[i] = a;
}

// ---------------------------------------------------------------------------
extern "C" void kernel_launch(void* const* d_in, const int* in_sizes, int n_in,
                              void* d_out, int out_size, void* d_ws, size_t ws_size,
                              hipStream_t stream) {
  const float* x  = (const float*)d_in[0];
  const float* Wg = (const float*)d_in[1];
  const float* bg = (const float*)d_in[2];
  const float* We = (const float*)d_in[3];
  const float* be = (const float*)d_in[4];
  float* out = (float*)d_out;

  // ws: xbf 16MB | WeT 32MB | g 512KB | p1 32MB  (total 80.5MB)
  char* ws = (char*)d_ws;
  unsigned short* xbf = (unsigned short*)ws;
  unsigned short* WeT = (unsigned short*)(ws + (size_t)NB * DIN * 2);
  float* g = (float*)(ws + (size_t)NB * DIN * 2 + (size_t)NE * DIN * DOUT * 2);
  float* p1 = (float*)(ws + (size_t)NB * DIN * 2 + (size_t)NE * DIN * DOUT * 2 +
                       (size_t)NB * NE * 4);

  gate_cast_kernel<<<dim3(NB / 4), 256, 0, stream>>>(x, Wg, bg, g, xbf);
  we_transpose_kernel<<<dim3(DOUT / 64, DIN / 64, NE), 256, 0, stream>>>(We, WeT);
  moe_gemm_kernel<<<dim3(256), 512, 0, stream>>>(xbf, WeT, g, be, out, p1);
  combine_kernel<<<dim3(NB * DOUT / 4 / 256), 256, 0, stream>>>(out, p1);
}

// Round 16
// 334.693 us; speedup vs baseline: 1.1447x; 1.0144x over previous
//
#include <hip/hip_runtime.h>
#include <hip/hip_bf16.h>

// Problem: B=8192, D_IN=1024, D_OUT=1024, E=16
#define NB 8192
#define DIN 1024
#define DOUT 1024
#define NE 16

// GEMM tile geometry: split-K=2 (8 experts per block), BM=BN=256, BK=64
#define BM 256
#define BN 256
#define BK 64
#define NT 128  // (8 experts * 1024) / 64

typedef __attribute__((ext_vector_type(8))) short bf16x8;
typedef __attribute__((ext_vector_type(4))) short short4_t;
typedef __attribute__((ext_vector_type(4))) float f32x4;

__device__ __forceinline__ unsigned short f32_to_bf16(float f) {
  unsigned int u = __float_as_uint(f);
  u += 0x7FFFu + ((u >> 16) & 1u);  // RNE
  return (unsigned short)(u >> 16);
}

__device__ __forceinline__ void gl_lds16(const void* gp, void* lp) {
  __builtin_amdgcn_global_load_lds(
      (const __attribute__((address_space(1))) void*)gp,
      (__attribute__((address_space(3))) void*)lp, 16, 0, 0);
}

#define SB __builtin_amdgcn_sched_barrier(0)

// ---------------- Kernel 1: gate softmax (f32) + x -> bf16 cast --------------
__global__ __launch_bounds__(256) void gate_cast_kernel(
    const float* __restrict__ x, const float* __restrict__ Wg,
    const float* __restrict__ bg, float* __restrict__ gout,
    unsigned short* __restrict__ xbf) {
  const int lane = threadIdx.x & 63;
  const int wid = threadIdx.x >> 6;
  const int row = blockIdx.x * 4 + wid;

  const f32x4* xr = (const f32x4*)(x + (size_t)row * DIN);
  f32x4 xv[4];
#pragma unroll
  for (int j = 0; j < 4; ++j) xv[j] = xr[j * 64 + lane];

  float acc[NE];
#pragma unroll
  for (int e = 0; e < NE; ++e) acc[e] = 0.f;

#pragma unroll
  for (int j = 0; j < 4; ++j) {
#pragma unroll
    for (int t = 0; t < 4; ++t) {
      const int i = j * 256 + lane * 4 + t;
      const f32x4* wrow = (const f32x4*)(Wg + (size_t)i * NE);
      const f32x4 w0 = wrow[0], w1 = wrow[1], w2 = wrow[2], w3 = wrow[3];
      const float xx = xv[j][t];
#pragma unroll
      for (int q = 0; q < 4; ++q) {
        acc[q]      = fmaf(xx, w0[q], acc[q]);
        acc[4 + q]  = fmaf(xx, w1[q], acc[4 + q]);
        acc[8 + q]  = fmaf(xx, w2[q], acc[8 + q]);
        acc[12 + q] = fmaf(xx, w3[q], acc[12 + q]);
      }
    }
  }
#pragma unroll
  for (int off = 32; off >= 1; off >>= 1) {
#pragma unroll
    for (int e = 0; e < NE; ++e) acc[e] += __shfl_xor(acc[e], off, 64);
  }
#pragma unroll
  for (int e = 0; e < NE; ++e) acc[e] += bg[e];
  float mx = acc[0];
#pragma unroll
  for (int e = 1; e < NE; ++e) mx = fmaxf(mx, acc[e]);
  float p[NE];
  float s = 0.f;
#pragma unroll
  for (int e = 0; e < NE; ++e) { p[e] = expf(acc[e] - mx); s += p[e]; }
  const float inv = 1.f / s;
  if (lane == 0) {
#pragma unroll
    for (int e = 0; e < NE; ++e) gout[(size_t)row * NE + e] = p[e] * inv;
  }
#pragma unroll
  for (int j = 0; j < 4; ++j) {
    short4_t o;
#pragma unroll
    for (int t = 0; t < 4; ++t) o[t] = (short)f32_to_bf16(xv[j][t]);
    *(short4_t*)(xbf + (size_t)row * DIN + j * 256 + lane * 4) = o;
  }
}

// ------------- Kernel 2: We[e,i,o] f32 -> WeT[e,o,i] bf16 (transpose) --------
__global__ __launch_bounds__(256) void we_transpose_kernel(
    const float* __restrict__ We, unsigned short* __restrict__ WeT) {
  __shared__ float tile[64][65];
  const int e = blockIdx.z, it = blockIdx.y, ot = blockIdx.x;
  const int tr = threadIdx.x >> 4;
  const int tc = (threadIdx.x & 15) * 4;
  const float* src = We + (((size_t)e * DIN + it * 64) * DOUT) + ot * 64;
#pragma unroll
  for (int rr = 0; rr < 64; rr += 16) {
    const f32x4 v = *(const f32x4*)(src + (size_t)(rr + tr) * DOUT + tc);
#pragma unroll
    for (int t = 0; t < 4; ++t) tile[rr + tr][tc + t] = v[t];
  }
  __syncthreads();
  unsigned short* dst = WeT + (((size_t)e * DOUT + ot * 64) * DIN) + it * 64;
#pragma unroll
  for (int rr = 0; rr < 64; rr += 16) {
    short4_t o;
#pragma unroll
    for (int t = 0; t < 4; ++t) o[t] = (short)f32_to_bf16(tile[tc + t][rr + tr]);
    *(short4_t*)(dst + (size_t)(rr + tr) * DIN + tc) = o;
  }
}

// ------------- Kernel 3: split-K MoE GEMM, 4 phases, 5 barriers/tile ---------
// 8 waves 2Mx4N, per-wave 128x64. P0 mi0-3/ks0, P1 mi0-3/ks1, P2 mi4-7/ks0,
// P3 mi4-7/ks1. One pre-MFMA barrier per phase + one boundary barrier.
// Minimal sched pins: one sched_barrier(0) after each s_barrier. Stage for
// t+1: P0 Bh0, P1 Bh1, P2 Ah0, P3 Ah1. Waits: end-P1 vmcnt(4) (drains this
// tile's Ah1 before P2 reads), boundary vmcnt(2). Never 0 mid-loop.
// Output: per-half bf16 partials (halves the partial write/read traffic).
__global__ __launch_bounds__(512, 2) void moe_gemm_kernel(
    const unsigned short* __restrict__ xbf,   // [8192][1024] bf16
    const unsigned short* __restrict__ WeT,   // [16][1024 o][1024 i] bf16
    const float* __restrict__ g,              // [8192][16]
    const float* __restrict__ be,             // [16][1024]
    unsigned short* __restrict__ p0,          // kh=0 partial, bf16
    unsigned short* __restrict__ p1) {        // kh=1 partial, bf16
  __shared__ __align__(16) unsigned short As[2][BM * BK];  // 2x32 KiB
  __shared__ __align__(16) unsigned short Bs[2][BN * BK];  // 2x32 KiB
  __shared__ float gs[BM][NE];                             // 16 KiB

  const int tid = threadIdx.x;
  const int lane = tid & 63, wid = tid >> 6;
  const int wm = wid >> 2, wn = wid & 3;
  const int l15 = lane & 15, l4 = lane >> 4;

  const int bid = blockIdx.x;
  const int xcd = bid & 7, jj_ = bid >> 3;
  const int kh = xcd >> 2;
  const int brow = ((xcd & 3) * 8 + (jj_ >> 2)) * BM;
  const int bcol = (jj_ & 3) * BN;
  unsigned short* const outp = kh ? p1 : p0;

  // precomputed per-thread LDS read bases; swizzle depends only on (l15,l4,ks)
  const int swz0 = (l4 * 16) ^ ((l15 & 7) << 4);
  const int swz1 = (64 + l4 * 16) ^ ((l15 & 7) << 4);
  const char* const ldsA0 = (const char*)&As[0][0] + (wm * 128 + l15) * 128 + swz0;
  const char* const ldsA1 = (const char*)&As[0][0] + (wm * 128 + l15) * 128 + swz1;
  const char* const ldsB0 = (const char*)&Bs[0][0] + (wn * 64 + l15) * 128 + swz0;
  const char* const ldsB1 = (const char*)&Bs[0][0] + (wn * 64 + l15) * 128 + swz1;

  // staging precompute (T2 both-sides: linear LDS dst, inverse-swz global src)
  const int srow = tid >> 3;
  const int lk = (((tid & 7) * 16) ^ ((srow & 7) << 4)) >> 1;
  const unsigned short* const aBase = xbf + (size_t)(brow + srow) * DIN + lk;
  const unsigned short* const bBase = WeT + (size_t)(bcol + srow) * DIN + lk;
  char* const ldsStA = (char*)&As[0][0] + wid * 1024;  // wave-uniform
  char* const ldsStB = (char*)&Bs[0][0] + wid * 1024;

#define STA(BUF, CR, KC) \
  gl_lds16(aBase + (size_t)(CR) * DIN + (KC), ldsStA + (BUF) * 32768 + (CR) * 128)
#define STB(BUF, CR, EOFF, KC) \
  gl_lds16(bBase + (EOFF) + (size_t)(CR) * DIN + (KC), \
           ldsStB + (BUF) * 32768 + (CR) * 128)
#define RD_B(KS, BUF)                                             \
  _Pragma("unroll") for (int ni = 0; ni < 4; ++ni)                \
      bfr[ni][KS] = *(const bf16x8*)(((KS) ? ldsB1 : ldsB0) +     \
                                     ni * 2048 + (BUF) * 32768);
#define RD_A(KS, MI0, BUF)                                        \
  _Pragma("unroll") for (int d = 0; d < 4; ++d)                   \
      af[d] = *(const bf16x8*)(((KS) ? ldsA1 : ldsA0) +           \
                               ((MI0) + d) * 2048 + (BUF) * 32768);
#define MFMA_P(MI0, KS)                                            \
  _Pragma("unroll") for (int d = 0; d < 4; ++d)                    \
  _Pragma("unroll") for (int ni = 0; ni < 4; ++ni)                 \
      acc[(MI0) + d][ni] = __builtin_amdgcn_mfma_f32_16x16x32_bf16(\
          af[d], bfr[ni][KS], acc[(MI0) + d][ni], 0, 0, 0);

  {  // gate tile -> LDS
    const f32x4* gsrc = (const f32x4*)(g + (size_t)brow * NE);
    f32x4* gdst = (f32x4*)&gs[0][0];
    gdst[tid] = gsrc[tid];
    gdst[tid + 512] = gsrc[tid + 512];
  }

  // prologue: stage tile 0, deadline order Bh0,Bh1,Ah0 then Ah1
  {
    const size_t e0 = (size_t)(kh * 8) * (size_t)(DIN * DOUT);
    STB(0, 0, e0, 0);  STB(0, 128, e0, 0);
    STB(0, 64, e0, 0); STB(0, 192, e0, 0);
    STA(0, 0, 0);      STA(0, 128, 0);
    STA(0, 64, 0);     STA(0, 192, 0);
  }

  f32x4 acc[8][4];
#pragma unroll
  for (int mi = 0; mi < 8; ++mi)
#pragma unroll
    for (int ni = 0; ni < 4; ++ni) acc[mi][ni] = (f32x4){0.f, 0.f, 0.f, 0.f};

  asm volatile("s_waitcnt vmcnt(2) lgkmcnt(0)" ::: "memory");
  __builtin_amdgcn_s_barrier(); SB;

  bf16x8 bfr[4][2], af[4];

#define TILE_BODY(T, BUF)                                                      \
  {                                                                            \
    const int t_ = (T);                                                        \
    const int kcN = ((t_ + 1) & 15) * 64;                                      \
    const size_t eoffN =                                                       \
        (size_t)(kh * 8 + ((t_ + 1) >> 4)) * (size_t)(DIN * DOUT);             \
    const bool hasNext = (t_ + 1) < NT;                                        \
    if ((t_ & 15) == 0 && t_ > 0) { /* expert boundary rescale */              \
      const int e = kh * 8 + (t_ >> 4);                                        \
      _Pragma("unroll") for (int mi = 0; mi < 8; ++mi) {                       \
        const int rb = wm * 128 + mi * 16 + l4 * 4;                            \
        _Pragma("unroll") for (int q = 0; q < 4; ++q) {                        \
          const float r = gs[rb + q][e - 1] *                                  \
                          __builtin_amdgcn_rcpf(fmaxf(gs[rb + q][e], 1e-30f)); \
          _Pragma("unroll") for (int ni = 0; ni < 4; ++ni)                     \
              acc[mi][ni][q] *= r;                                             \
        }                                                                      \
      }                                                                        \
    }                                                                          \
    /* ===== P0: mi0-3, ks0 ===== */                                           \
    RD_B(0, BUF); RD_A(0, 0, BUF);                                             \
    if (hasNext) { STB(BUF ^ 1, 0, eoffN, kcN); STB(BUF ^ 1, 128, eoffN, kcN); } \
    __builtin_amdgcn_s_barrier(); SB;                                          \
    __builtin_amdgcn_s_setprio(1); MFMA_P(0, 0);                               \
    __builtin_amdgcn_s_setprio(0);                                             \
    /* ===== P1: mi0-3, ks1 ===== */                                           \
    RD_B(1, BUF); RD_A(1, 0, BUF);                                             \
    if (hasNext) { STB(BUF ^ 1, 64, eoffN, kcN); STB(BUF ^ 1, 192, eoffN, kcN); } \
    if (t_ == NT - 1) { asm volatile("s_waitcnt vmcnt(0)" ::: "memory"); }     \
    else { asm volatile("s_waitcnt vmcnt(4)" ::: "memory"); }                  \
    __builtin_amdgcn_s_barrier(); SB;                                          \
    __builtin_amdgcn_s_setprio(1); MFMA_P(0, 1);                               \
    __builtin_amdgcn_s_setprio(0);                                             \
    /* ===== P2: mi4-7, ks0 ===== */                                           \
    RD_A(0, 4, BUF);                                                           \
    if (hasNext) { STA(BUF ^ 1, 0, kcN); STA(BUF ^ 1, 128, kcN); }             \
    __builtin_amdgcn_s_barrier(); SB;                                          \
    __builtin_amdgcn_s_setprio(1); MFMA_P(4, 0);                               \
    __builtin_amdgcn_s_setprio(0);                                             \
    /* ===== P3: mi4-7, ks1 ===== */                                           \
    RD_A(1, 4, BUF);                                                           \
    if (hasNext) { STA(BUF ^ 1, 64, kcN); STA(BUF ^ 1, 192, kcN); }            \
    __builtin_amdgcn_s_barrier(); SB;                                          \
    __builtin_amdgcn_s_setprio(1); MFMA_P(4, 1);                               \
    __builtin_amdgcn_s_setprio(0);                                             \
    if ((t_ & 15) == 15) { /* bias for expert e */                             \
      const int e = kh * 8 + (t_ >> 4);                                        \
      _Pragma("unroll") for (int ni = 0; ni < 4; ++ni) {                       \
        const float bv = be[e * DOUT + bcol + wn * 64 + ni * 16 + l15];        \
        _Pragma("unroll") for (int mi = 0; mi < 8; ++mi)                       \
          _Pragma("unroll") for (int q = 0; q < 4; ++q)                        \
              acc[mi][ni][q] += bv;                                            \
      }                                                                        \
    }                                                                          \
    if (t_ < NT - 1) { asm volatile("s_waitcnt vmcnt(2)" ::: "memory"); }      \
    __builtin_amdgcn_s_barrier(); SB;                                          \
  }

  for (int tt = 0; tt < NT; tt += 2) {
    TILE_BODY(tt, 0);
    TILE_BODY(tt + 1, 1);
  }

  // epilogue: scale by this half's last gate, store bf16 partial
  const int eL = kh * 8 + 7;
#pragma unroll
  for (int mi = 0; mi < 8; ++mi) {
    const int rb = wm * 128 + mi * 16 + l4 * 4;
#pragma unroll
    for (int q = 0; q < 4; ++q) {
      const float gf = gs[rb + q][eL];
      unsigned short* const orp =
          outp + (size_t)(brow + rb + q) * DOUT + bcol + wn * 64 + l15;
      orp[0]  = f32_to_bf16(acc[mi][0][q] * gf);
      orp[16] = f32_to_bf16(acc[mi][1][q] * gf);
      orp[32] = f32_to_bf16(acc[mi][2][q] * gf);
      orp[48] = f32_to_bf16(acc[mi][3][q] * gf);
    }
  }
#undef TILE_BODY
#undef MFMA_P
#undef RD_A
#undef RD_B
#undef STA
#undef STB
}

// -------- Kernel 4: combine out = f32(p0) + f32(p1)  (bf16 partials) --------
__global__ __launch_bounds__(256) void combine_kernel(
    float* __restrict__ out, const unsigned short* __restrict__ p0,
    const unsigned short* __restrict__ p1) {
  const size_t i = ((size_t)blockIdx.x * 256 + threadIdx.x) * 8;
  const short4_t a0 = *(const short4_t*)(p0 + i);
  const short4_t a1 = *(const short4_t*)(p0 + i + 4);
  const short4_t b0 = *(const short4_t*)(p1 + i);
  const short4_t b1 = *(const short4_t*)(p1 + i + 4);
  f32x4 r0, r1;
#pragma unroll
  for (int q = 0; q < 4; ++q) {
    r0[q] = __uint_as_float((unsigned)(unsigned short)a0[q] << 16) +
            __uint_as_float((unsigned)(unsigned short)b0[q] << 16);
    r1[q] = __uint_as_float((unsigned)(unsigned short)a1[q] << 16) +
            __uint_as_float((unsigned)(unsigned short)b1[q] << 16);
  }
  *(f32x4*)(out + i) = r0;
  *(f32x4*)(out + i + 4) = r1;
}

// ---------------------------------------------------------------------------
extern "C" void kernel_launch(void* const* d_in, const int* in_sizes, int n_in,
                              void* d_out, int out_size, void* d_ws, size_t ws_size,
                              hipStream_t stream) {
  const float* x  = (const float*)d_in[0];
  const float* Wg = (const float*)d_in[1];
  const float* bg = (const float*)d_in[2];
  const float* We = (const float*)d_in[3];
  const float* be = (const float*)d_in[4];
  float* out = (float*)d_out;

  // ws: xbf 16MB | WeT 32MB | g 512KB | p0 16MB | p1 16MB  (total 80.5MB)
  char* ws = (char*)d_ws;
  unsigned short* xbf = (unsigned short*)ws;
  unsigned short* WeT = (unsigned short*)(ws + (size_t)NB * DIN * 2);
  float* g = (float*)(ws + (size_t)NB * DIN * 2 + (size_t)NE * DIN * DOUT * 2);
  unsigned short* p0 =
      (unsigned short*)(ws + (size_t)NB * DIN * 2 +
                        (size_t)NE * DIN * DOUT * 2 + (size_t)NB * NE * 4);
  unsigned short* p1 = p0 + (size_t)NB * DOUT;

  gate_cast_kernel<<<dim3(NB / 4), 256, 0, stream>>>(x, Wg, bg, g, xbf);
  we_transpose_kernel<<<dim3(DOUT / 64, DIN / 64, NE), 256, 0, stream>>>(We, WeT);
  moe_gemm_kernel<<<dim3(256), 512, 0, stream>>>(xbf, WeT, g, be, p0, p1);
  combine_kernel<<<dim3(NB * DOUT / 8 / 256), 256, 0, stream>>>(out, p0, p1);
}

// Round 17
// 330.873 us; speedup vs baseline: 1.1579x; 1.0115x over previous
//
#include <hip/hip_runtime.h>
#include <hip/hip_bf16.h>

// Problem: B=8192, D_IN=1024, D_OUT=1024, E=16
#define NB 8192
#define DIN 1024
#define DOUT 1024
#define NE 16

// GEMM tile geometry: split-K=2 (8 experts per block), BM=BN=256, BK=64
#define BM 256
#define BN 256
#define BK 64
#define NT 128  // (8 experts * 1024) / 64

typedef __attribute__((ext_vector_type(8))) short bf16x8;
typedef __attribute__((ext_vector_type(4))) short short4_t;
typedef __attribute__((ext_vector_type(4))) float f32x4;

__device__ __forceinline__ unsigned short f32_to_bf16(float f) {
  unsigned int u = __float_as_uint(f);
  u += 0x7FFFu + ((u >> 16) & 1u);  // RNE
  return (unsigned short)(u >> 16);
}

__device__ __forceinline__ void gl_lds16(const void* gp, void* lp) {
  __builtin_amdgcn_global_load_lds(
      (const __attribute__((address_space(1))) void*)gp,
      (__attribute__((address_space(3))) void*)lp, 16, 0, 0);
}

#define SB __builtin_amdgcn_sched_barrier(0)

// ------ Kernel 1: fused prep -- We transpose+cast AND gate softmax+cast ------
// Blocks [0,4096): We[e,i,o] f32 -> WeT[e,o,i] bf16 (64x64 LDS-tiled).
// Blocks [4096,6144): gate logits+softmax (wave/row) + x -> bf16 cast.
__global__ __launch_bounds__(256) void prep_kernel(
    const float* __restrict__ x, const float* __restrict__ Wg,
    const float* __restrict__ bg, const float* __restrict__ We,
    float* __restrict__ gout, unsigned short* __restrict__ xbf,
    unsigned short* __restrict__ WeT) {
  if (blockIdx.x < 4096) {
    // ---------------- We transpose + cast ----------------
    __shared__ float tile[64][65];
    const int t = blockIdx.x;
    const int e = t >> 8, it = (t >> 4) & 15, ot = t & 15;
    const int tr = threadIdx.x >> 4;
    const int tc = (threadIdx.x & 15) * 4;
    const float* src = We + (((size_t)e * DIN + it * 64) * DOUT) + ot * 64;
#pragma unroll
    for (int rr = 0; rr < 64; rr += 16) {
      const f32x4 v = *(const f32x4*)(src + (size_t)(rr + tr) * DOUT + tc);
#pragma unroll
      for (int q = 0; q < 4; ++q) tile[rr + tr][tc + q] = v[q];
    }
    __syncthreads();
    unsigned short* dst = WeT + (((size_t)e * DOUT + ot * 64) * DIN) + it * 64;
#pragma unroll
    for (int rr = 0; rr < 64; rr += 16) {
      short4_t o;
#pragma unroll
      for (int q = 0; q < 4; ++q)
        o[q] = (short)f32_to_bf16(tile[tc + q][rr + tr]);
      *(short4_t*)(dst + (size_t)(rr + tr) * DIN + tc) = o;
    }
  } else {
    // ---------------- gate softmax + x cast ----------------
    const int lane = threadIdx.x & 63;
    const int wid = threadIdx.x >> 6;
    const int row = (blockIdx.x - 4096) * 4 + wid;

    const f32x4* xr = (const f32x4*)(x + (size_t)row * DIN);
    f32x4 xv[4];
#pragma unroll
    for (int j = 0; j < 4; ++j) xv[j] = xr[j * 64 + lane];

    float acc[NE];
#pragma unroll
    for (int e = 0; e < NE; ++e) acc[e] = 0.f;

#pragma unroll
    for (int j = 0; j < 4; ++j) {
#pragma unroll
      for (int t2 = 0; t2 < 4; ++t2) {
        const int i = j * 256 + lane * 4 + t2;
        const f32x4* wrow = (const f32x4*)(Wg + (size_t)i * NE);
        const f32x4 w0 = wrow[0], w1 = wrow[1], w2 = wrow[2], w3 = wrow[3];
        const float xx = xv[j][t2];
#pragma unroll
        for (int q = 0; q < 4; ++q) {
          acc[q]      = fmaf(xx, w0[q], acc[q]);
          acc[4 + q]  = fmaf(xx, w1[q], acc[4 + q]);
          acc[8 + q]  = fmaf(xx, w2[q], acc[8 + q]);
          acc[12 + q] = fmaf(xx, w3[q], acc[12 + q]);
        }
      }
    }
#pragma unroll
    for (int off = 32; off >= 1; off >>= 1) {
#pragma unroll
      for (int e = 0; e < NE; ++e) acc[e] += __shfl_xor(acc[e], off, 64);
    }
#pragma unroll
    for (int e = 0; e < NE; ++e) acc[e] += bg[e];
    float mx = acc[0];
#pragma unroll
    for (int e = 1; e < NE; ++e) mx = fmaxf(mx, acc[e]);
    float p[NE];
    float s = 0.f;
#pragma unroll
    for (int e = 0; e < NE; ++e) { p[e] = expf(acc[e] - mx); s += p[e]; }
    const float inv = 1.f / s;
    if (lane == 0) {
#pragma unroll
      for (int e = 0; e < NE; ++e) gout[(size_t)row * NE + e] = p[e] * inv;
    }
#pragma unroll
    for (int j = 0; j < 4; ++j) {
      short4_t o;
#pragma unroll
      for (int t2 = 0; t2 < 4; ++t2) o[t2] = (short)f32_to_bf16(xv[j][t2]);
      *(short4_t*)(xbf + (size_t)row * DIN + j * 256 + lane * 4) = o;
    }
  }
}

// ------------- Kernel 3: split-K MoE GEMM, 4 phases, 5 barriers/tile ---------
// 8 waves 2Mx4N, per-wave 128x64. P0 mi0-3/ks0, P1 mi0-3/ks1, P2 mi4-7/ks0,
// P3 mi4-7/ks1. One pre-MFMA barrier per phase + one boundary barrier.
// Minimal sched pins: one sched_barrier(0) after each s_barrier. Stage for
// t+1: P0 Bh0, P1 Bh1, P2 Ah0, P3 Ah1. Waits: end-P1 vmcnt(4) (drains this
// tile's Ah1 before P2 reads), boundary vmcnt(2). Never 0 mid-loop.
// Output: per-half bf16 partials (halves the partial write/read traffic).
__global__ __launch_bounds__(512, 2) void moe_gemm_kernel(
    const unsigned short* __restrict__ xbf,   // [8192][1024] bf16
    const unsigned short* __restrict__ WeT,   // [16][1024 o][1024 i] bf16
    const float* __restrict__ g,              // [8192][16]
    const float* __restrict__ be,             // [16][1024]
    unsigned short* __restrict__ p0,          // kh=0 partial, bf16
    unsigned short* __restrict__ p1) {        // kh=1 partial, bf16
  __shared__ __align__(16) unsigned short As[2][BM * BK];  // 2x32 KiB
  __shared__ __align__(16) unsigned short Bs[2][BN * BK];  // 2x32 KiB
  __shared__ float gs[BM][NE];                             // 16 KiB

  const int tid = threadIdx.x;
  const int lane = tid & 63, wid = tid >> 6;
  const int wm = wid >> 2, wn = wid & 3;
  const int l15 = lane & 15, l4 = lane >> 4;

  const int bid = blockIdx.x;
  const int xcd = bid & 7, jj_ = bid >> 3;
  const int kh = xcd >> 2;
  const int brow = ((xcd & 3) * 8 + (jj_ >> 2)) * BM;
  const int bcol = (jj_ & 3) * BN;
  unsigned short* const outp = kh ? p1 : p0;

  // precomputed per-thread LDS read bases; swizzle depends only on (l15,l4,ks)
  const int swz0 = (l4 * 16) ^ ((l15 & 7) << 4);
  const int swz1 = (64 + l4 * 16) ^ ((l15 & 7) << 4);
  const char* const ldsA0 = (const char*)&As[0][0] + (wm * 128 + l15) * 128 + swz0;
  const char* const ldsA1 = (const char*)&As[0][0] + (wm * 128 + l15) * 128 + swz1;
  const char* const ldsB0 = (const char*)&Bs[0][0] + (wn * 64 + l15) * 128 + swz0;
  const char* const ldsB1 = (const char*)&Bs[0][0] + (wn * 64 + l15) * 128 + swz1;

  // staging precompute (T2 both-sides: linear LDS dst, inverse-swz global src)
  const int srow = tid >> 3;
  const int lk = (((tid & 7) * 16) ^ ((srow & 7) << 4)) >> 1;
  const unsigned short* const aBase = xbf + (size_t)(brow + srow) * DIN + lk;
  const unsigned short* const bBase = WeT + (size_t)(bcol + srow) * DIN + lk;
  char* const ldsStA = (char*)&As[0][0] + wid * 1024;  // wave-uniform
  char* const ldsStB = (char*)&Bs[0][0] + wid * 1024;

#define STA(BUF, CR, KC) \
  gl_lds16(aBase + (size_t)(CR) * DIN + (KC), ldsStA + (BUF) * 32768 + (CR) * 128)
#define STB(BUF, CR, EOFF, KC) \
  gl_lds16(bBase + (EOFF) + (size_t)(CR) * DIN + (KC), \
           ldsStB + (BUF) * 32768 + (CR) * 128)
#define RD_B(KS, BUF)                                             \
  _Pragma("unroll") for (int ni = 0; ni < 4; ++ni)                \
      bfr[ni][KS] = *(const bf16x8*)(((KS) ? ldsB1 : ldsB0) +     \
                                     ni * 2048 + (BUF) * 32768);
#define RD_A(KS, MI0, BUF)                                        \
  _Pragma("unroll") for (int d = 0; d < 4; ++d)                   \
      af[d] = *(const bf16x8*)(((KS) ? ldsA1 : ldsA0) +           \
                               ((MI0) + d) * 2048 + (BUF) * 32768);
#define MFMA_P(MI0, KS)                                            \
  _Pragma("unroll") for (int d = 0; d < 4; ++d)                    \
  _Pragma("unroll") for (int ni = 0; ni < 4; ++ni)                 \
      acc[(MI0) + d][ni] = __builtin_amdgcn_mfma_f32_16x16x32_bf16(\
          af[d], bfr[ni][KS], acc[(MI0) + d][ni], 0, 0, 0);

  {  // gate tile -> LDS
    const f32x4* gsrc = (const f32x4*)(g + (size_t)brow * NE);
    f32x4* gdst = (f32x4*)&gs[0][0];
    gdst[tid] = gsrc[tid];
    gdst[tid + 512] = gsrc[tid + 512];
  }

  // prologue: stage tile 0, deadline order Bh0,Bh1,Ah0 then Ah1
  {
    const size_t e0 = (size_t)(kh * 8) * (size_t)(DIN * DOUT);
    STB(0, 0, e0, 0);  STB(0, 128, e0, 0);
    STB(0, 64, e0, 0); STB(0, 192, e0, 0);
    STA(0, 0, 0);      STA(0, 128, 0);
    STA(0, 64, 0);     STA(0, 192, 0);
  }

  f32x4 acc[8][4];
#pragma unroll
  for (int mi = 0; mi < 8; ++mi)
#pragma unroll
    for (int ni = 0; ni < 4; ++ni) acc[mi][ni] = (f32x4){0.f, 0.f, 0.f, 0.f};

  asm volatile("s_waitcnt vmcnt(2) lgkmcnt(0)" ::: "memory");
  __builtin_amdgcn_s_barrier(); SB;

  bf16x8 bfr[4][2], af[4];

#define TILE_BODY(T, BUF)                                                      \
  {                                                                            \
    const int t_ = (T);                                                        \
    const int kcN = ((t_ + 1) & 15) * 64;                                      \
    const size_t eoffN =                                                       \
        (size_t)(kh * 8 + ((t_ + 1) >> 4)) * (size_t)(DIN * DOUT);             \
    const bool hasNext = (t_ + 1) < NT;                                        \
    if ((t_ & 15) == 0 && t_ > 0) { /* expert boundary rescale */              \
      const int e = kh * 8 + (t_ >> 4);                                        \
      _Pragma("unroll") for (int mi = 0; mi < 8; ++mi) {                       \
        const int rb = wm * 128 + mi * 16 + l4 * 4;                            \
        _Pragma("unroll") for (int q = 0; q < 4; ++q) {                        \
          const float r = gs[rb + q][e - 1] *                                  \
                          __builtin_amdgcn_rcpf(fmaxf(gs[rb + q][e], 1e-30f)); \
          _Pragma("unroll") for (int ni = 0; ni < 4; ++ni)                     \
              acc[mi][ni][q] *= r;                                             \
        }                                                                      \
      }                                                                        \
    }                                                                          \
    /* ===== P0: mi0-3, ks0 ===== */                                           \
    RD_B(0, BUF); RD_A(0, 0, BUF);                                             \
    if (hasNext) { STB(BUF ^ 1, 0, eoffN, kcN); STB(BUF ^ 1, 128, eoffN, kcN); } \
    __builtin_amdgcn_s_barrier(); SB;                                          \
    __builtin_amdgcn_s_setprio(1); MFMA_P(0, 0);                               \
    __builtin_amdgcn_s_setprio(0);                                             \
    /* ===== P1: mi0-3, ks1 ===== */                                           \
    RD_B(1, BUF); RD_A(1, 0, BUF);                                             \
    if (hasNext) { STB(BUF ^ 1, 64, eoffN, kcN); STB(BUF ^ 1, 192, eoffN, kcN); } \
    if (t_ == NT - 1) { asm volatile("s_waitcnt vmcnt(0)" ::: "memory"); }     \
    else { asm volatile("s_waitcnt vmcnt(4)" ::: "memory"); }                  \
    __builtin_amdgcn_s_barrier(); SB;                                          \
    __builtin_amdgcn_s_setprio(1); MFMA_P(0, 1);                               \
    __builtin_amdgcn_s_setprio(0);                                             \
    /* ===== P2: mi4-7, ks0 ===== */                                           \
    RD_A(0, 4, BUF);                                                           \
    if (hasNext) { STA(BUF ^ 1, 0, kcN); STA(BUF ^ 1, 128, kcN); }             \
    __builtin_amdgcn_s_barrier(); SB;                                          \
    __builtin_amdgcn_s_setprio(1); MFMA_P(4, 0);                               \
    __builtin_amdgcn_s_setprio(0);                                             \
    /* ===== P3: mi4-7, ks1 ===== */                                           \
    RD_A(1, 4, BUF);                                                           \
    if (hasNext) { STA(BUF ^ 1, 64, kcN); STA(BUF ^ 1, 192, kcN); }            \
    __builtin_amdgcn_s_barrier(); SB;                                          \
    __builtin_amdgcn_s_setprio(1); MFMA_P(4, 1);                               \
    __builtin_amdgcn_s_setprio(0);                                             \
    if ((t_ & 15) == 15) { /* bias for expert e */                             \
      const int e = kh * 8 + (t_ >> 4);                                        \
      _Pragma("unroll") for (int ni = 0; ni < 4; ++ni) {                       \
        const float bv = be[e * DOUT + bcol + wn * 64 + ni * 16 + l15];        \
        _Pragma("unroll") for (int mi = 0; mi < 8; ++mi)                       \
          _Pragma("unroll") for (int q = 0; q < 4; ++q)                        \
              acc[mi][ni][q] += bv;                                            \
      }                                                                        \
    }                                                                          \
    if (t_ < NT - 1) { asm volatile("s_waitcnt vmcnt(2)" ::: "memory"); }      \
    __builtin_amdgcn_s_barrier(); SB;                                          \
  }

  for (int tt = 0; tt < NT; tt += 2) {
    TILE_BODY(tt, 0);
    TILE_BODY(tt + 1, 1);
  }

  // epilogue: scale by this half's last gate, store bf16 partial
  const int eL = kh * 8 + 7;
#pragma unroll
  for (int mi = 0; mi < 8; ++mi) {
    const int rb = wm * 128 + mi * 16 + l4 * 4;
#pragma unroll
    for (int q = 0; q < 4; ++q) {
      const float gf = gs[rb + q][eL];
      unsigned short* const orp =
          outp + (size_t)(brow + rb + q) * DOUT + bcol + wn * 64 + l15;
      orp[0]  = f32_to_bf16(acc[mi][0][q] * gf);
      orp[16] = f32_to_bf16(acc[mi][1][q] * gf);
      orp[32] = f32_to_bf16(acc[mi][2][q] * gf);
      orp[48] = f32_to_bf16(acc[mi][3][q] * gf);
    }
  }
#undef TILE_BODY
#undef MFMA_P
#undef RD_A
#undef RD_B
#undef STA
#undef STB
}

// -------- Kernel 4: combine out = f32(p0) + f32(p1)  (bf16 partials) --------
__global__ __launch_bounds__(256) void combine_kernel(
    float* __restrict__ out, const unsigned short* __restrict__ p0,
    const unsigned short* __restrict__ p1) {
  const size_t i = ((size_t)blockIdx.x * 256 + threadIdx.x) * 8;
  const short4_t a0 = *(const short4_t*)(p0 + i);
  const short4_t a1 = *(const short4_t*)(p0 + i + 4);
  const short4_t b0 = *(const short4_t*)(p1 + i);
  const short4_t b1 = *(const short4_t*)(p1 + i + 4);
  f32x4 r0, r1;
#pragma unroll
  for (int q = 0; q < 4; ++q) {
    r0[q] = __uint_as_float((unsigned)(unsigned short)a0[q] << 16) +
            __uint_as_float((unsigned)(unsigned short)b0[q] << 16);
    r1[q] = __uint_as_float((unsigned)(unsigned short)a1[q] << 16) +
            __uint_as_float((unsigned)(unsigned short)b1[q] << 16);
  }
  *(f32x4*)(out + i) = r0;
  *(f32x4*)(out + i + 4) = r1;
}

// ---------------------------------------------------------------------------
extern "C" void kernel_launch(void* const* d_in, const int* in_sizes, int n_in,
                              void* d_out, int out_size, void* d_ws, size_t ws_size,
                              hipStream_t stream) {
  const float* x  = (const float*)d_in[0];
  const float* Wg = (const float*)d_in[1];
  const float* bg = (const float*)d_in[2];
  const float* We = (const float*)d_in[3];
  const float* be = (const float*)d_in[4];
  float* out = (float*)d_out;

  // ws: xbf 16MB | WeT 32MB | g 512KB | p0 16MB | p1 16MB  (total 80.5MB)
  char* ws = (char*)d_ws;
  unsigned short* xbf = (unsigned short*)ws;
  unsigned short* WeT = (unsigned short*)(ws + (size_t)NB * DIN * 2);
  float* g = (float*)(ws + (size_t)NB * DIN * 2 + (size_t)NE * DIN * DOUT * 2);
  unsigned short* p0 =
      (unsigned short*)(ws + (size_t)NB * DIN * 2 +
                        (size_t)NE * DIN * DOUT * 2 + (size_t)NB * NE * 4);
  unsigned short* p1 = p0 + (size_t)NB * DOUT;

  prep_kernel<<<dim3(4096 + NB / 4), 256, 0, stream>>>(x, Wg, bg, We, g, xbf,
                                                       WeT);
  moe_gemm_kernel<<<dim3(256), 512, 0, stream>>>(xbf, WeT, g, be, p0, p1);
  combine_kernel<<<dim3(NB * DOUT / 8 / 256), 256, 0, stream>>>(out, p0, p1);
}